// Round 8
// baseline (631.894 us; speedup 1.0000x reference)
//
#include <hip/hip_runtime.h>
#include <math.h>

// Problem constants: N=100000, E=400000, G=64, IN=8, H=4, C=64, HD=256.
// GEMMs: split-bf16 MFMA (hi+lo, 3-term) for fp32-class accuracy.
// R8: gemm_mfma -> 128-row blocks, k-panel (32) double-buffered LDS staging
// (one barrier/panel; staging overlaps MFMA within the block). Wave grid =
// 8 ct-groups x 2 rt-groups, acc 64 VGPR. Encoder fused into gemm<64>
// staging. prep_w / zero kernels merged; scatter uses pre-zeroed cursor.

#define HD 256
#define NHEAD 4
#define CH 64

typedef __attribute__((ext_vector_type(8))) short bf16x8;
typedef __attribute__((ext_vector_type(4))) float f32x4;

__device__ __forceinline__ unsigned f2bf_hibits(float f) {
    unsigned u = __float_as_uint(f);
    return (u + 0x7fffu + ((u >> 16) & 1u)) & 0xffff0000u;   // RNE, as high bits
}

// ---------------------------------------------------------------------------
__global__ void zero_int(int* __restrict__ p, int n) {
    int i = blockIdx.x * 256 + threadIdx.x;
    if (i < n) p[i] = 0;
}

// ---------------------------------------------------------------------------
// CSR build: degree histogram -> 3-step exclusive scan -> scatter (gathers
// src and eattr into CSR order; cursor array pre-zeroed by zero_int pass).
// ---------------------------------------------------------------------------
__global__ void deg_kernel(const int* __restrict__ dst, int* __restrict__ cnt, int E) {
    int e = blockIdx.x * 256 + threadIdx.x;
    if (e < E) atomicAdd(&cnt[dst[e]], 1);
}

__global__ void scan_block(const int* __restrict__ cnt, int* __restrict__ off,
                           int* __restrict__ bsum, int N) {
    __shared__ int s[256];
    int i = blockIdx.x * 256 + threadIdx.x;
    int v = (i < N) ? cnt[i] : 0;
    s[threadIdx.x] = v;
    __syncthreads();
    for (int d = 1; d < 256; d <<= 1) {
        int t = 0;
        if (threadIdx.x >= d) t = s[threadIdx.x - d];
        __syncthreads();
        s[threadIdx.x] += t;
        __syncthreads();
    }
    if (i < N) off[i + 1] = s[threadIdx.x];
    if (threadIdx.x == 255) bsum[blockIdx.x] = s[255];
    if (blockIdx.x == 0 && threadIdx.x == 0) off[0] = 0;
}

__global__ void scan_bsum(const int* __restrict__ bsum, int* __restrict__ bpre, int nb) {
    __shared__ int s[512];
    int t = threadIdx.x;
    s[t] = (t < nb) ? bsum[t] : 0;
    __syncthreads();
    for (int d = 1; d < 512; d <<= 1) {
        int x = 0;
        if (t >= d) x = s[t - d];
        __syncthreads();
        s[t] += x;
        __syncthreads();
    }
    if (t < nb) bpre[t] = s[t] - bsum[t];
}

__global__ void scan_add(int* __restrict__ off, const int* __restrict__ bpre, int N) {
    int i = blockIdx.x * 256 + threadIdx.x;
    if (i < N) off[i + 1] += bpre[blockIdx.x];
}

__global__ void scatter_kernel(const int* __restrict__ dst, const int* __restrict__ src,
                               const float* __restrict__ eattr, const int* __restrict__ off,
                               int* __restrict__ cur, int* __restrict__ srcg,
                               float* __restrict__ eag, int E) {
    int e = blockIdx.x * 256 + threadIdx.x;
    if (e < E) {
        int d = dst[e];
        int p = atomicAdd(&cur[d], 1);
        int t = off[d] + p;
        srcg[t] = src[e];
        eag[t] = eattr[e];
    }
}

// ---------------------------------------------------------------------------
// prep_w: Wl,Wr [K,256] fp32 -> B-frag layout. hi region then lo region.
// Lane holds B[k=(l>>4)*8+j][n=l&15] of tile (ks,ct); ct<16->Wl, else Wr.
// ---------------------------------------------------------------------------
__device__ __forceinline__ void prep_one(const float* Wl, const float* Wr,
                                         ushort* frag, int K, int t) {
    int total = K * 64;
    int l = t & 63;
    int ct = (t >> 6) & 31;
    int ks = t >> 11;
    int n = l & 15, q = l >> 4;
    const float* W = (ct < 16) ? Wl : Wr;
    int col = (ct & 15) * 16 + n;
    ushort* phi = frag + (size_t)t * 8;
    ushort* plo = frag + (size_t)total * 8 + (size_t)t * 8;
#pragma unroll
    for (int j = 0; j < 8; ++j) {
        int k = ks * 32 + q * 8 + j;
        float wv = W[(size_t)k * 256 + col];
        unsigned h = f2bf_hibits(wv);
        phi[j] = (ushort)(h >> 16);
        float lof = wv - __uint_as_float(h);
        plo[j] = (ushort)(f2bf_hibits(lof) >> 16);
    }
}

__global__ void prep_w_all(const float* __restrict__ Wl1, const float* __restrict__ Wr1,
                           ushort* __restrict__ f1,
                           const float* __restrict__ Wl2, const float* __restrict__ Wr2,
                           ushort* __restrict__ f2) {
    int gt = blockIdx.x * 256 + threadIdx.x;
    if (gt < 64 * 64) prep_one(Wl1, Wr1, f1, 64, gt);
    else if (gt < 64 * 64 + 256 * 64) prep_one(Wl2, Wr2, f2, 256, gt - 64 * 64);
}

// ---------------------------------------------------------------------------
// Split-bf16 MFMA dual GEMM (R8): 128 rows/block, 1024 thr (16 waves).
// K-panel (32) double-buffered: stage panel ks+1 (global->regs->LDS frags)
// while MFMAing panel ks; ONE barrier per panel. Wave w: ct-group = w&7
// (4 col-tiles), rt-group = w>>3 (4 row-tiles). acc[4][4] = 64 VGPR.
// FUSE_ENC: A is x[N,8], panel values computed as relu(x@Wenc+benc).
// outR may alias A (panel reads precede epilogue; blocks own disjoint rows).
// ---------------------------------------------------------------------------
template <int K, bool FUSE_ENC>
__global__ __launch_bounds__(1024, 4) void gemm_mfma(
    const float* A, const float* __restrict__ Wenc, const float* __restrict__ benc,
    const ushort* __restrict__ Bfrag,
    const float* __restrict__ bl, const float* __restrict__ br,
    float* __restrict__ outL, float* outR, int N) {
    constexpr int KS = K / 32;
    constexpr size_t LO_OFF = (size_t)K * 64 * 8;   // shorts
    __shared__ ushort pan[2][2][8 * 64 * 8];        // [buf][hi/lo][cell shorts] 32 KB

    const int t = threadIdx.x;
    const int row0 = blockIdx.x * 128;

    // staging: thread -> (row sr, k-chunk sc4): one float4 per panel
    const int sr = t >> 3;          // 0..127
    const int sc4 = t & 7;          // k-local = sc4*4 + j
    const int srow = row0 + sr;
    const int scell = ((sr >> 4) * 64 + (sc4 >> 1) * 16 + (sr & 15)) * 8 + (sc4 & 1) * 4;

    auto load_panel = [&](int ks) -> float4 {
        if constexpr (FUSE_ENC) {
            float xr[8];
#pragma unroll
            for (int u = 0; u < 8; ++u)
                xr[u] = (srow < N) ? A[(size_t)srow * 8 + u] : 0.f;
            float o[4];
#pragma unroll
            for (int j = 0; j < 4; ++j) {
                int c = ks * 32 + sc4 * 4 + j;
                float a = benc[c];
#pragma unroll
                for (int u = 0; u < 8; ++u) a = fmaf(xr[u], Wenc[u * 64 + c], a);
                o[j] = fmaxf(a, 0.f);
            }
            return make_float4(o[0], o[1], o[2], o[3]);
        } else {
            float4 v = make_float4(0.f, 0.f, 0.f, 0.f);
            if (srow < N) v = *(const float4*)(A + (size_t)srow * K + ks * 32 + sc4 * 4);
            return v;
        }
    };
    auto store_panel = [&](int buf, float4 v) {
        float f[4] = {v.x, v.y, v.z, v.w};
        ushort h4[4], l4[4];
#pragma unroll
        for (int u = 0; u < 4; ++u) {
            unsigned hb = f2bf_hibits(f[u]);
            h4[u] = (ushort)(hb >> 16);
            l4[u] = (ushort)(f2bf_hibits(f[u] - __uint_as_float(hb)) >> 16);
        }
        *(ushort4*)(&pan[buf][0][scell]) = make_ushort4(h4[0], h4[1], h4[2], h4[3]);
        *(ushort4*)(&pan[buf][1][scell]) = make_ushort4(l4[0], l4[1], l4[2], l4[3]);
    };

    // prologue: stage panel 0
    store_panel(0, load_panel(0));
    __syncthreads();

    const int w = t >> 6, l = t & 63;
    const int ct0 = (w & 7) * 4;     // 4 col-tiles (ct0..ct0+3, never crosses 16)
    const int rtb = (w >> 3) * 4;    // 4 row-tiles

    f32x4 acc[4][4];                 // [rt][c]
#pragma unroll
    for (int rt = 0; rt < 4; ++rt)
#pragma unroll
        for (int c = 0; c < 4; ++c) acc[rt][c] = (f32x4){0.f, 0.f, 0.f, 0.f};

    for (int ks = 0; ks < KS; ++ks) {
        const int cur = ks & 1;
        float4 nv;
        if (ks + 1 < KS) nv = load_panel(ks + 1);   // global loads issued early
        bf16x8 ah[4], al[4];
#pragma unroll
        for (int rt = 0; rt < 4; ++rt) {
            int cell = ((rtb + rt) * 64 + l) * 8;
            ah[rt] = *(const bf16x8*)(&pan[cur][0][cell]);
            al[rt] = *(const bf16x8*)(&pan[cur][1][cell]);
        }
#pragma unroll
        for (int c = 0; c < 4; ++c) {
            size_t e = ((size_t)(ks * 32 + ct0 + c) * 64 + l) * 8;
            bf16x8 bh = *(const bf16x8*)(Bfrag + e);
            bf16x8 bo = *(const bf16x8*)(Bfrag + LO_OFF + e);
#pragma unroll
            for (int rt = 0; rt < 4; ++rt) {
                acc[rt][c] = __builtin_amdgcn_mfma_f32_16x16x32_bf16(ah[rt], bh, acc[rt][c], 0, 0, 0);
                acc[rt][c] = __builtin_amdgcn_mfma_f32_16x16x32_bf16(al[rt], bh, acc[rt][c], 0, 0, 0);
                acc[rt][c] = __builtin_amdgcn_mfma_f32_16x16x32_bf16(ah[rt], bo, acc[rt][c], 0, 0, 0);
            }
        }
        if (ks + 1 < KS) store_panel(cur ^ 1, nv);  // other buffer: no race
        __syncthreads();
    }

    // epilogue: C layout col = lane&15, row = (lane>>4)*4 + reg
    const int m = l & 15, q = l >> 4;
    const float* bias = (ct0 < 16) ? bl : br;
    float* outp = (ct0 < 16) ? outL : outR;
#pragma unroll
    for (int c = 0; c < 4; ++c) {
        int colbase = ((ct0 + c) & 15) * 16 + m;
        float bb = bias[colbase];
#pragma unroll
        for (int rt = 0; rt < 4; ++rt) {
#pragma unroll
            for (int r = 0; r < 4; ++r) {
                int row = row0 + (rtb + rt) * 16 + q * 4 + r;
                if (row < N) outp[(size_t)row * 256 + colbase] = acc[rt][c][r] + bb;
            }
        }
    }
}

// ---------------------------------------------------------------------------
// GATv2 aggregation (R6): wave per node; lane = head*16 + quarter; each lane
// owns 4 consecutive channels (float4) of one head. Per edge: coalesced
// float4 gather of xl[src], 16-lane quadrant reduction (4 heads in parallel),
// 2 __expf online-softmax update. out may ALIAS xr.
// ---------------------------------------------------------------------------
__global__ __launch_bounds__(256) void gat_aggregate(
    const float* __restrict__ xl, const float* xr,
    const int* __restrict__ off, const int* __restrict__ srcg,
    const float* __restrict__ eag,
    const float* __restrict__ We, const float* __restrict__ att,
    const float* __restrict__ bias, float* out, int N) {
    int node = blockIdx.x * 4 + (threadIdx.x >> 6);
    if (node >= N) return;
    int lane = threadIdx.x & 63;
    int cbase = (lane >> 4) * 64 + (lane & 15) * 4;

    float4 we4 = *(const float4*)(We + cbase);
    float4 at4 = *(const float4*)(att + cbase);
    size_t nb = (size_t)node * HD;
    float4 xr4 = *(const float4*)(xr + nb + cbase);
    float4 b4 = *(const float4*)(bias + cbase);

    float m = -1e30f, l = 0.f;
    float4 acc = make_float4(0.f, 0.f, 0.f, 0.f);

    int s0 = off[node], s1 = off[node + 1];
    for (int t = s0; t < s1; ++t) {
        int j = srcg[t];
        float ea = eag[t];
        float4 xl4 = *(const float4*)(xl + (size_t)j * HD + cbase);
        float v0 = fmaf(ea, we4.x, xl4.x + xr4.x);
        float v1 = fmaf(ea, we4.y, xl4.y + xr4.y);
        float v2 = fmaf(ea, we4.z, xl4.z + xr4.z);
        float v3 = fmaf(ea, we4.w, xl4.w + xr4.w);
        v0 = fmaf(0.2f, fminf(v0, 0.f), fmaxf(v0, 0.f));
        v1 = fmaf(0.2f, fminf(v1, 0.f), fmaxf(v1, 0.f));
        v2 = fmaf(0.2f, fminf(v2, 0.f), fmaxf(v2, 0.f));
        v3 = fmaf(0.2f, fminf(v3, 0.f), fmaxf(v3, 0.f));
        float r = at4.x * v0;
        r = fmaf(at4.y, v1, r);
        r = fmaf(at4.z, v2, r);
        r = fmaf(at4.w, v3, r);
        r += __shfl_xor(r, 1);
        r += __shfl_xor(r, 2);
        r += __shfl_xor(r, 4);
        r += __shfl_xor(r, 8);
        float mn = fmaxf(m, r);
        float sc = __expf(m - mn);
        float p = __expf(r - mn);
        l = fmaf(l, sc, p);
        acc.x = fmaf(acc.x, sc, p * xl4.x);
        acc.y = fmaf(acc.y, sc, p * xl4.y);
        acc.z = fmaf(acc.z, sc, p * xl4.z);
        acc.w = fmaf(acc.w, sc, p * xl4.w);
        m = mn;
    }
    float inv = 1.f / (l + 1e-16f);
    float4 o;
    o.x = fmaxf(fmaf(acc.x, inv, b4.x), 0.f);
    o.y = fmaxf(fmaf(acc.y, inv, b4.y), 0.f);
    o.z = fmaxf(fmaf(acc.z, inv, b4.z), 0.f);
    o.w = fmaxf(fmaf(acc.w, inv, b4.w), 0.f);
    *(float4*)(out + nb + cbase) = o;
}

// ---------------------------------------------------------------------------
__device__ __forceinline__ int lowerb(const int* b, int n, int v) {
    int lo = 0, hi = n;
    while (lo < hi) {
        int mid = (lo + hi) >> 1;
        if (b[mid] < v) lo = mid + 1; else hi = mid;
    }
    return lo;
}

__global__ void pool_kernel(const float* __restrict__ h, const int* __restrict__ batch,
                            float* __restrict__ pooled, float* __restrict__ gcnt, int N) {
    int g = blockIdx.x >> 3, part = blockIdx.x & 7;
    int start = lowerb(batch, N, g);
    int end = lowerb(batch, N, g + 1);
    int rows = end - start;
    int r0 = start + (int)((long long)rows * part / 8);
    int r1 = start + (int)((long long)rows * (part + 1) / 8);
    int c = threadIdx.x;
    float s = 0.f;
    for (int r = r0; r < r1; ++r) s += h[(size_t)r * HD + c];
    atomicAdd(&pooled[g * HD + c], s);
    if (part == 0 && c == 0) gcnt[g] = (float)rows;
}

// ---------------------------------------------------------------------------
__global__ void mlp_kernel(const float* __restrict__ pooled, const float* __restrict__ gcnt,
                           const float* __restrict__ W_p1, const float* __restrict__ b_p1,
                           const float* __restrict__ ln_g, const float* __restrict__ ln_b,
                           const float* __restrict__ W_p2, const float* __restrict__ b_p2,
                           const float* __restrict__ W_head, const float* __restrict__ b_head,
                           float* __restrict__ out) {
    int g = blockIdx.x;
    int j = threadIdx.x;
    __shared__ float sh[128];
    __shared__ float red[2];

    float inv = 1.f / fmaxf(gcnt[g], 1.f);
    float v = b_p1[j];
    for (int k = 0; k < 256; ++k) v = fmaf(pooled[g * 256 + k] * inv, W_p1[k * 128 + j], v);

    float s = v;
    for (int o = 32; o > 0; o >>= 1) s += __shfl_xor(s, o);
    if ((j & 63) == 0) red[j >> 6] = s;
    __syncthreads();
    float mu = (red[0] + red[1]) * (1.f / 128.f);
    float d = v - mu;
    float s2 = d * d;
    for (int o = 32; o > 0; o >>= 1) s2 += __shfl_xor(s2, o);
    __syncthreads();
    if ((j & 63) == 0) red[j >> 6] = s2;
    __syncthreads();
    float var = (red[0] + red[1]) * (1.f / 128.f);

    float p = d * rsqrtf(var + 1e-5f) * ln_g[j] + ln_b[j];
    sh[j] = fmaxf(p, 0.f);
    __syncthreads();

    if (j < 64) {
        float q = b_p2[j];
        for (int k = 0; k < 128; ++k) q = fmaf(sh[k], W_p2[k * 64 + j], q);
        q = fmaxf(q, 0.f);
        float t = q * W_head[j];
        for (int o = 32; o > 0; o >>= 1) t += __shfl_xor(t, o);
        if (j == 0) out[g] = t + b_head[0];
    }
}

// ---------------------------------------------------------------------------
extern "C" void kernel_launch(void* const* d_in, const int* in_sizes, int n_in,
                              void* d_out, int out_size, void* d_ws, size_t ws_size,
                              hipStream_t stream) {
    const float* x      = (const float*)d_in[0];
    const float* eattr  = (const float*)d_in[1];
    const int*   src    = (const int*)d_in[2];
    const int*   dst    = (const int*)d_in[3];
    const int*   batch  = (const int*)d_in[4];
    const float* W_enc  = (const float*)d_in[5];
    const float* b_enc  = (const float*)d_in[6];
    const float* g1_Wl  = (const float*)d_in[7];
    const float* g1_bl  = (const float*)d_in[8];
    const float* g1_Wr  = (const float*)d_in[9];
    const float* g1_br  = (const float*)d_in[10];
    const float* g1_We  = (const float*)d_in[11];
    const float* g1_att = (const float*)d_in[12];
    const float* g1_bias= (const float*)d_in[13];
    const float* g2_Wl  = (const float*)d_in[14];
    const float* g2_bl  = (const float*)d_in[15];
    const float* g2_Wr  = (const float*)d_in[16];
    const float* g2_br  = (const float*)d_in[17];
    const float* g2_We  = (const float*)d_in[18];
    const float* g2_att = (const float*)d_in[19];
    const float* g2_bias= (const float*)d_in[20];
    const float* W_p1   = (const float*)d_in[21];
    const float* b_p1   = (const float*)d_in[22];
    const float* ln_g   = (const float*)d_in[23];
    const float* ln_b   = (const float*)d_in[24];
    const float* W_p2   = (const float*)d_in[25];
    const float* b_p2   = (const float*)d_in[26];
    const float* W_head = (const float*)d_in[27];
    const float* b_head = (const float*)d_in[28];

    const int N = in_sizes[0] / 8;   // 100000
    const int E = in_sizes[2];       // 400000

    // workspace layout (~212 MB)
    char* p = (char*)d_ws;
    auto alloc = [&](size_t bytes) -> void* {
        void* r = (void*)p;
        p += (bytes + 255) & ~(size_t)255;
        return r;
    };
    float*  bufA   = (float*)alloc((size_t)N * HD * 4);   // XR / h (in-place chain)
    float*  bufXL  = (float*)alloc((size_t)N * HD * 4);   // XL (gather target)
    // contiguous zero region: cnt, cur, pooled
    int*    cnt    = (int*)alloc((size_t)N * 4);
    int*    curp   = (int*)alloc((size_t)N * 4);
    float*  pooled = (float*)alloc(64 * HD * 4);
    char*   zend   = p;
    int*    off    = (int*)alloc((size_t)(N + 1) * 4);
    int*    srcg   = (int*)alloc((size_t)E * 4);
    float*  eag    = (float*)alloc((size_t)E * 4);
    const int nb   = (N + 255) / 256;
    int*    bsum   = (int*)alloc((size_t)nb * 4);
    int*    bpre   = (int*)alloc((size_t)nb * 4);
    float*  gcnt   = (float*)alloc(64 * 4);
    ushort* wfrag1 = (ushort*)alloc((size_t)64 * 64 * 16 * 2 * 2);   // K=64 hi+lo
    ushort* wfrag2 = (ushort*)alloc((size_t)256 * 64 * 16 * 2 * 2);  // K=256 hi+lo

    const int nzero = (int)(((char*)zend - (char*)cnt) / 4);

    // ---- zero cnt/cur/pooled in one pass; weight prep in one pass ----
    zero_int<<<(nzero + 255) / 256, 256, 0, stream>>>(cnt, nzero);
    prep_w_all<<<(64 * 64 + 256 * 64 + 255) / 256, 256, 0, stream>>>(
        g1_Wl, g1_Wr, wfrag1, g2_Wl, g2_Wr, wfrag2);

    // ---- CSR by dst ----
    deg_kernel<<<(E + 255) / 256, 256, 0, stream>>>(dst, cnt, E);
    scan_block<<<nb, 256, 0, stream>>>(cnt, off, bsum, N);
    scan_bsum<<<1, 512, 0, stream>>>(bsum, bpre, nb);
    scan_add<<<nb, 256, 0, stream>>>(off, bpre, N);
    scatter_kernel<<<(E + 255) / 256, 256, 0, stream>>>(dst, src, eattr, off, curp,
                                                        srcg, eag, E);

    const int gblocks = (N + 127) / 128;

    // ---- GAT layer 1 (encoder fused into staging): x -> XL(bufXL), XR(bufA)
    gemm_mfma<64, true><<<gblocks, 1024, 0, stream>>>(
        x, W_enc, b_enc, wfrag1, g1_bl, g1_br, bufXL, bufA, N);
    gat_aggregate<<<(N + 3) / 4, 256, 0, stream>>>(
        bufXL, bufA, off, srcg, eag, g1_We, g1_att, g1_bias, bufA, N);

    // ---- GAT layer 2: h1(bufA) -> XL(bufXL), XR in-place(bufA)
    gemm_mfma<256, false><<<gblocks, 1024, 0, stream>>>(
        bufA, bufA, bufA, wfrag2, g2_bl, g2_br, bufXL, bufA, N);
    gat_aggregate<<<(N + 3) / 4, 256, 0, stream>>>(
        bufXL, bufA, off, srcg, eag, g2_We, g2_att, g2_bias, bufA, N);

    // ---- pool + MLP head ----
    pool_kernel<<<64 * 8, 256, 0, stream>>>(bufA, batch, pooled, gcnt, N);
    mlp_kernel<<<64, 128, 0, stream>>>(pooled, gcnt, W_p1, b_p1, ln_g, ln_b,
                                       W_p2, b_p2, W_head, b_head, (float*)d_out);
}

// Round 9
// 606.390 us; speedup vs baseline: 1.0421x; 1.0421x over previous
//
#include <hip/hip_runtime.h>
#include <math.h>

// Problem constants: N=100000, E=400000, G=64, IN=8, H=4, C=64, HD=256.
// GEMMs: split-bf16 MFMA (hi+lo, 3-term), R6 structure (512 thr, 64 rows,
// single barrier) — best measured (117 us @ K=256).
// R9: gat_aggregate batches edges x4: 4 independent gathers in flight,
// one merged online-softmax rescale per batch (5 expf vs 8).

#define HD 256
#define NHEAD 4
#define CH 64

typedef __attribute__((ext_vector_type(8))) short bf16x8;
typedef __attribute__((ext_vector_type(4))) float f32x4;

__device__ __forceinline__ unsigned f2bf_hibits(float f) {
    unsigned u = __float_as_uint(f);
    return (u + 0x7fffu + ((u >> 16) & 1u)) & 0xffff0000u;   // RNE, as high bits
}

// ---------------------------------------------------------------------------
__global__ void zero_int(int* __restrict__ p, int n) {
    int i = blockIdx.x * 256 + threadIdx.x;
    if (i < n) p[i] = 0;
}

// ---------------------------------------------------------------------------
// CSR build: degree histogram -> 3-step exclusive scan -> scatter (gathers
// src and eattr into CSR order; cursor pre-zeroed in the merged zero pass).
// ---------------------------------------------------------------------------
__global__ void deg_kernel(const int* __restrict__ dst, int* __restrict__ cnt, int E) {
    int e = blockIdx.x * 256 + threadIdx.x;
    if (e < E) atomicAdd(&cnt[dst[e]], 1);
}

__global__ void scan_block(const int* __restrict__ cnt, int* __restrict__ off,
                           int* __restrict__ bsum, int N) {
    __shared__ int s[256];
    int i = blockIdx.x * 256 + threadIdx.x;
    int v = (i < N) ? cnt[i] : 0;
    s[threadIdx.x] = v;
    __syncthreads();
    for (int d = 1; d < 256; d <<= 1) {
        int t = 0;
        if (threadIdx.x >= d) t = s[threadIdx.x - d];
        __syncthreads();
        s[threadIdx.x] += t;
        __syncthreads();
    }
    if (i < N) off[i + 1] = s[threadIdx.x];
    if (threadIdx.x == 255) bsum[blockIdx.x] = s[255];
    if (blockIdx.x == 0 && threadIdx.x == 0) off[0] = 0;
}

__global__ void scan_bsum(const int* __restrict__ bsum, int* __restrict__ bpre, int nb) {
    __shared__ int s[512];
    int t = threadIdx.x;
    s[t] = (t < nb) ? bsum[t] : 0;
    __syncthreads();
    for (int d = 1; d < 512; d <<= 1) {
        int x = 0;
        if (t >= d) x = s[t - d];
        __syncthreads();
        s[t] += x;
        __syncthreads();
    }
    if (t < nb) bpre[t] = s[t] - bsum[t];
}

__global__ void scan_add(int* __restrict__ off, const int* __restrict__ bpre, int N) {
    int i = blockIdx.x * 256 + threadIdx.x;
    if (i < N) off[i + 1] += bpre[blockIdx.x];
}

__global__ void scatter_kernel(const int* __restrict__ dst, const int* __restrict__ src,
                               const float* __restrict__ eattr, const int* __restrict__ off,
                               int* __restrict__ cur, int* __restrict__ srcg,
                               float* __restrict__ eag, int E) {
    int e = blockIdx.x * 256 + threadIdx.x;
    if (e < E) {
        int d = dst[e];
        int p = atomicAdd(&cur[d], 1);
        int t = off[d] + p;
        srcg[t] = src[e];
        eag[t] = eattr[e];
    }
}

// ---------------------------------------------------------------------------
// Encoder: h0[N,64] = relu(x[N,8] @ W_enc[8,64] + b_enc)
// ---------------------------------------------------------------------------
__global__ void encoder_kernel(const float* __restrict__ x, const float* __restrict__ W,
                               const float* __restrict__ b, float* __restrict__ h, int N) {
    int idx = blockIdx.x * 256 + threadIdx.x;
    if (idx >= N * 64) return;
    int n = idx >> 6, c = idx & 63;
    float v = b[c];
#pragma unroll
    for (int k = 0; k < 8; ++k) v = fmaf(x[n * 8 + k], W[k * 64 + c], v);
    h[idx] = fmaxf(v, 0.f);
}

// ---------------------------------------------------------------------------
// prep_w: Wl,Wr [K,256] fp32 -> B-frag layout. hi region then lo region.
// Lane holds B[k=(l>>4)*8+j][n=l&15] of tile (ks,ct); ct<16->Wl, else Wr.
// ---------------------------------------------------------------------------
__device__ __forceinline__ void prep_one(const float* Wl, const float* Wr,
                                         ushort* frag, int K, int t) {
    int total = K * 64;
    int l = t & 63;
    int ct = (t >> 6) & 31;
    int ks = t >> 11;
    int n = l & 15, q = l >> 4;
    const float* W = (ct < 16) ? Wl : Wr;
    int col = (ct & 15) * 16 + n;
    ushort* phi = frag + (size_t)t * 8;
    ushort* plo = frag + (size_t)total * 8 + (size_t)t * 8;
#pragma unroll
    for (int j = 0; j < 8; ++j) {
        int k = ks * 32 + q * 8 + j;
        float wv = W[(size_t)k * 256 + col];
        unsigned h = f2bf_hibits(wv);
        phi[j] = (ushort)(h >> 16);
        float lof = wv - __uint_as_float(h);
        plo[j] = (ushort)(f2bf_hibits(lof) >> 16);
    }
}

__global__ void prep_w_all(const float* __restrict__ Wl1, const float* __restrict__ Wr1,
                           ushort* __restrict__ f1,
                           const float* __restrict__ Wl2, const float* __restrict__ Wr2,
                           ushort* __restrict__ f2) {
    int gt = blockIdx.x * 256 + threadIdx.x;
    if (gt < 64 * 64) prep_one(Wl1, Wr1, f1, 64, gt);
    else if (gt < 64 * 64 + 256 * 64) prep_one(Wl2, Wr2, f2, 256, gt - 64 * 64);
}

// ---------------------------------------------------------------------------
// Split-bf16 MFMA dual GEMM (R6 structure): 512 thr (8 waves), 64 rows.
// Staging converts A to hi/lo bf16 A-frags in LDS; one barrier; wave w owns
// ct = w*4..w*4+3, all 4 row-tiles. outR may alias A.
// ---------------------------------------------------------------------------
template <int K>
__global__ __launch_bounds__(512, 4) void gemm_mfma(
    const float* A, const ushort* __restrict__ Bfrag,
    const float* __restrict__ bl, const float* __restrict__ br,
    float* __restrict__ outL, float* outR, int N) {
    constexpr int KS = K / 32;
    constexpr int C4 = K / 4;
    constexpr int LC4 = (K == 256) ? 6 : 4;
    constexpr int FRAG_SHORTS = KS * 4 * 64 * 8;
    constexpr size_t LO_OFF = (size_t)K * 64 * 8;
    __shared__ ushort fragHi[FRAG_SHORTS];
    __shared__ ushort fragLo[FRAG_SHORTS];

    const int t = threadIdx.x;
    const int row0 = blockIdx.x * 64;

#pragma unroll
    for (int it = 0; it < (64 * C4) / 512; ++it) {
        int jj = it * 512 + t;
        int m = jj & 15;
        int c4 = (jj >> 4) & (C4 - 1);
        int rg = jj >> (4 + LC4);
        int row = row0 + rg * 16 + m;
        float4 v = make_float4(0.f, 0.f, 0.f, 0.f);
        if (row < N) v = *(const float4*)(A + (size_t)row * K + c4 * 4);
        int c = c4 * 4;
        int ks = c >> 5, q = (c >> 3) & 3, j = c & 7;
        int cell = (ks * 4 + rg) * 64 + m + 16 * q;
        float f[4] = {v.x, v.y, v.z, v.w};
        ushort h4[4], l4[4];
#pragma unroll
        for (int u = 0; u < 4; ++u) {
            unsigned hb = f2bf_hibits(f[u]);
            h4[u] = (ushort)(hb >> 16);
            l4[u] = (ushort)(f2bf_hibits(f[u] - __uint_as_float(hb)) >> 16);
        }
        *(ushort4*)(fragHi + cell * 8 + j) = make_ushort4(h4[0], h4[1], h4[2], h4[3]);
        *(ushort4*)(fragLo + cell * 8 + j) = make_ushort4(l4[0], l4[1], l4[2], l4[3]);
    }
    __syncthreads();

    const int w = t >> 6, l = t & 63;
    const int ct0 = w * 4;

    f32x4 acc[4][4];
#pragma unroll
    for (int rt = 0; rt < 4; ++rt)
#pragma unroll
        for (int c = 0; c < 4; ++c) acc[rt][c] = (f32x4){0.f, 0.f, 0.f, 0.f};

    for (int ks = 0; ks < KS; ++ks) {
        bf16x8 ah[4], al[4];
#pragma unroll
        for (int rt = 0; rt < 4; ++rt) {
            int cell = (ks * 4 + rt) * 64 + l;
            ah[rt] = *(const bf16x8*)(fragHi + cell * 8);
            al[rt] = *(const bf16x8*)(fragLo + cell * 8);
        }
#pragma unroll
        for (int c = 0; c < 4; ++c) {
            size_t e = ((size_t)(ks * 32 + ct0 + c) * 64 + l) * 8;
            bf16x8 bh = *(const bf16x8*)(Bfrag + e);
            bf16x8 bo = *(const bf16x8*)(Bfrag + LO_OFF + e);
#pragma unroll
            for (int rt = 0; rt < 4; ++rt) {
                acc[rt][c] = __builtin_amdgcn_mfma_f32_16x16x32_bf16(ah[rt], bh, acc[rt][c], 0, 0, 0);
                acc[rt][c] = __builtin_amdgcn_mfma_f32_16x16x32_bf16(al[rt], bh, acc[rt][c], 0, 0, 0);
                acc[rt][c] = __builtin_amdgcn_mfma_f32_16x16x32_bf16(ah[rt], bo, acc[rt][c], 0, 0, 0);
            }
        }
    }

    const int m = l & 15, q = l >> 4;
    const float* bias = (w < 4) ? bl : br;
    float* outp = (w < 4) ? outL : outR;
#pragma unroll
    for (int c = 0; c < 4; ++c) {
        int colbase = ((ct0 + c) & 15) * 16 + m;
        float bb = bias[colbase];
#pragma unroll
        for (int rt = 0; rt < 4; ++rt) {
#pragma unroll
            for (int r = 0; r < 4; ++r) {
                int row = row0 + rt * 16 + q * 4 + r;
                if (row < N) outp[(size_t)row * 256 + colbase] = acc[rt][c][r] + bb;
            }
        }
    }
}

// ---------------------------------------------------------------------------
// GATv2 aggregation (R9): wave per node; lane = head*16 + quarter owns 4
// consecutive channels of one head. Edges processed in batches of 4:
// 4 srcg/eag loads -> 4 INDEPENDENT xl gathers in flight -> 4 logit
// reductions (interleaved) -> one merged online-softmax update (1 rescale,
// 5 expf). Wave-uniform batch guard (no lane divergence).
// out may ALIAS xr.
// ---------------------------------------------------------------------------
__global__ __launch_bounds__(256) void gat_aggregate(
    const float* __restrict__ xl, const float* xr,
    const int* __restrict__ off, const int* __restrict__ srcg,
    const float* __restrict__ eag,
    const float* __restrict__ We, const float* __restrict__ att,
    const float* __restrict__ bias, float* out, int N) {
    int node = blockIdx.x * 4 + (threadIdx.x >> 6);
    if (node >= N) return;
    int lane = threadIdx.x & 63;
    int cbase = (lane >> 4) * 64 + (lane & 15) * 4;

    float4 we4 = *(const float4*)(We + cbase);
    float4 at4 = *(const float4*)(att + cbase);
    size_t nb = (size_t)node * HD;
    float4 xr4 = *(const float4*)(xr + nb + cbase);
    float4 b4 = *(const float4*)(bias + cbase);

    float m = -1e30f, l = 0.f;
    float4 acc = make_float4(0.f, 0.f, 0.f, 0.f);

    int s0 = off[node], s1 = off[node + 1];
    for (int t = s0; t < s1; t += 4) {
        int nE = s1 - t;                 // wave-uniform
        if (nE > 4) nE = 4;
        int j[4];
        float ea[4];
        float4 xv[4];
        float r[4];
#pragma unroll
        for (int u = 0; u < 4; ++u) {
            j[u] = (u < nE) ? srcg[t + u] : 0;
            ea[u] = (u < nE) ? eag[t + u] : 0.f;
        }
#pragma unroll
        for (int u = 0; u < 4; ++u) {
            xv[u] = make_float4(0.f, 0.f, 0.f, 0.f);
            if (u < nE) xv[u] = *(const float4*)(xl + (size_t)j[u] * HD + cbase);
        }
#pragma unroll
        for (int u = 0; u < 4; ++u) {
            float v0 = fmaf(ea[u], we4.x, xv[u].x + xr4.x);
            float v1 = fmaf(ea[u], we4.y, xv[u].y + xr4.y);
            float v2 = fmaf(ea[u], we4.z, xv[u].z + xr4.z);
            float v3 = fmaf(ea[u], we4.w, xv[u].w + xr4.w);
            v0 = fmaf(0.2f, fminf(v0, 0.f), fmaxf(v0, 0.f));
            v1 = fmaf(0.2f, fminf(v1, 0.f), fmaxf(v1, 0.f));
            v2 = fmaf(0.2f, fminf(v2, 0.f), fmaxf(v2, 0.f));
            v3 = fmaf(0.2f, fminf(v3, 0.f), fmaxf(v3, 0.f));
            float rr = at4.x * v0;
            rr = fmaf(at4.y, v1, rr);
            rr = fmaf(at4.z, v2, rr);
            rr = fmaf(at4.w, v3, rr);
            r[u] = rr;
        }
        // 4 independent 16-lane reductions (chains interleave)
#pragma unroll
        for (int u = 0; u < 4; ++u) {
            r[u] += __shfl_xor(r[u], 1);
            r[u] += __shfl_xor(r[u], 2);
            r[u] += __shfl_xor(r[u], 4);
            r[u] += __shfl_xor(r[u], 8);
            if (u >= nE) r[u] = -1e30f;
        }
        // merged online-softmax update (single rescale)
        float rmax = fmaxf(fmaxf(r[0], r[1]), fmaxf(r[2], r[3]));
        float mn = fmaxf(m, rmax);
        float sc = __expf(m - mn);
        float p0 = __expf(r[0] - mn);
        float p1 = __expf(r[1] - mn);
        float p2 = __expf(r[2] - mn);
        float p3 = __expf(r[3] - mn);
        l = fmaf(l, sc, p0 + p1 + p2 + p3);
        acc.x = fmaf(acc.x, sc, fmaf(p0, xv[0].x, fmaf(p1, xv[1].x, fmaf(p2, xv[2].x, p3 * xv[3].x))));
        acc.y = fmaf(acc.y, sc, fmaf(p0, xv[0].y, fmaf(p1, xv[1].y, fmaf(p2, xv[2].y, p3 * xv[3].y))));
        acc.z = fmaf(acc.z, sc, fmaf(p0, xv[0].z, fmaf(p1, xv[1].z, fmaf(p2, xv[2].z, p3 * xv[3].z))));
        acc.w = fmaf(acc.w, sc, fmaf(p0, xv[0].w, fmaf(p1, xv[1].w, fmaf(p2, xv[2].w, p3 * xv[3].w))));
        m = mn;
    }
    float inv = 1.f / (l + 1e-16f);
    float4 o;
    o.x = fmaxf(fmaf(acc.x, inv, b4.x), 0.f);
    o.y = fmaxf(fmaf(acc.y, inv, b4.y), 0.f);
    o.z = fmaxf(fmaf(acc.z, inv, b4.z), 0.f);
    o.w = fmaxf(fmaf(acc.w, inv, b4.w), 0.f);
    *(float4*)(out + nb + cbase) = o;
}

// ---------------------------------------------------------------------------
__device__ __forceinline__ int lowerb(const int* b, int n, int v) {
    int lo = 0, hi = n;
    while (lo < hi) {
        int mid = (lo + hi) >> 1;
        if (b[mid] < v) lo = mid + 1; else hi = mid;
    }
    return lo;
}

__global__ void pool_kernel(const float* __restrict__ h, const int* __restrict__ batch,
                            float* __restrict__ pooled, float* __restrict__ gcnt, int N) {
    int g = blockIdx.x >> 3, part = blockIdx.x & 7;
    int start = lowerb(batch, N, g);
    int end = lowerb(batch, N, g + 1);
    int rows = end - start;
    int r0 = start + (int)((long long)rows * part / 8);
    int r1 = start + (int)((long long)rows * (part + 1) / 8);
    int c = threadIdx.x;
    float s = 0.f;
    for (int r = r0; r < r1; ++r) s += h[(size_t)r * HD + c];
    atomicAdd(&pooled[g * HD + c], s);
    if (part == 0 && c == 0) gcnt[g] = (float)rows;
}

// ---------------------------------------------------------------------------
__global__ void mlp_kernel(const float* __restrict__ pooled, const float* __restrict__ gcnt,
                           const float* __restrict__ W_p1, const float* __restrict__ b_p1,
                           const float* __restrict__ ln_g, const float* __restrict__ ln_b,
                           const float* __restrict__ W_p2, const float* __restrict__ b_p2,
                           const float* __restrict__ W_head, const float* __restrict__ b_head,
                           float* __restrict__ out) {
    int g = blockIdx.x;
    int j = threadIdx.x;
    __shared__ float sh[128];
    __shared__ float red[2];

    float inv = 1.f / fmaxf(gcnt[g], 1.f);
    float v = b_p1[j];
    for (int k = 0; k < 256; ++k) v = fmaf(pooled[g * 256 + k] * inv, W_p1[k * 128 + j], v);

    float s = v;
    for (int o = 32; o > 0; o >>= 1) s += __shfl_xor(s, o);
    if ((j & 63) == 0) red[j >> 6] = s;
    __syncthreads();
    float mu = (red[0] + red[1]) * (1.f / 128.f);
    float d = v - mu;
    float s2 = d * d;
    for (int o = 32; o > 0; o >>= 1) s2 += __shfl_xor(s2, o);
    __syncthreads();
    if ((j & 63) == 0) red[j >> 6] = s2;
    __syncthreads();
    float var = (red[0] + red[1]) * (1.f / 128.f);

    float p = d * rsqrtf(var + 1e-5f) * ln_g[j] + ln_b[j];
    sh[j] = fmaxf(p, 0.f);
    __syncthreads();

    if (j < 64) {
        float q = b_p2[j];
        for (int k = 0; k < 128; ++k) q = fmaf(sh[k], W_p2[k * 64 + j], q);
        q = fmaxf(q, 0.f);
        float t = q * W_head[j];
        for (int o = 32; o > 0; o >>= 1) t += __shfl_xor(t, o);
        if (j == 0) out[g] = t + b_head[0];
    }
}

// ---------------------------------------------------------------------------
extern "C" void kernel_launch(void* const* d_in, const int* in_sizes, int n_in,
                              void* d_out, int out_size, void* d_ws, size_t ws_size,
                              hipStream_t stream) {
    const float* x      = (const float*)d_in[0];
    const float* eattr  = (const float*)d_in[1];
    const int*   src    = (const int*)d_in[2];
    const int*   dst    = (const int*)d_in[3];
    const int*   batch  = (const int*)d_in[4];
    const float* W_enc  = (const float*)d_in[5];
    const float* b_enc  = (const float*)d_in[6];
    const float* g1_Wl  = (const float*)d_in[7];
    const float* g1_bl  = (const float*)d_in[8];
    const float* g1_Wr  = (const float*)d_in[9];
    const float* g1_br  = (const float*)d_in[10];
    const float* g1_We  = (const float*)d_in[11];
    const float* g1_att = (const float*)d_in[12];
    const float* g1_bias= (const float*)d_in[13];
    const float* g2_Wl  = (const float*)d_in[14];
    const float* g2_bl  = (const float*)d_in[15];
    const float* g2_Wr  = (const float*)d_in[16];
    const float* g2_br  = (const float*)d_in[17];
    const float* g2_We  = (const float*)d_in[18];
    const float* g2_att = (const float*)d_in[19];
    const float* g2_bias= (const float*)d_in[20];
    const float* W_p1   = (const float*)d_in[21];
    const float* b_p1   = (const float*)d_in[22];
    const float* ln_g   = (const float*)d_in[23];
    const float* ln_b   = (const float*)d_in[24];
    const float* W_p2   = (const float*)d_in[25];
    const float* b_p2   = (const float*)d_in[26];
    const float* W_head = (const float*)d_in[27];
    const float* b_head = (const float*)d_in[28];

    const int N = in_sizes[0] / 8;   // 100000
    const int E = in_sizes[2];       // 400000

    // workspace layout (~236 MB)
    char* p = (char*)d_ws;
    auto alloc = [&](size_t bytes) -> void* {
        void* r = (void*)p;
        p += (bytes + 255) & ~(size_t)255;
        return r;
    };
    float*  bufA   = (float*)alloc((size_t)N * HD * 4);   // XR / h (in-place chain)
    float*  bufXL  = (float*)alloc((size_t)N * HD * 4);   // XL (gather target)
    float*  bufH0  = (float*)alloc((size_t)N * CH * 4);   // encoder output
    // contiguous zero region: cnt, cur, pooled
    int*    cnt    = (int*)alloc((size_t)N * 4);
    int*    curp   = (int*)alloc((size_t)N * 4);
    float*  pooled = (float*)alloc(64 * HD * 4);
    char*   zend   = p;
    int*    off    = (int*)alloc((size_t)(N + 1) * 4);
    int*    srcg   = (int*)alloc((size_t)E * 4);
    float*  eag    = (float*)alloc((size_t)E * 4);
    const int nb   = (N + 255) / 256;
    int*    bsum   = (int*)alloc((size_t)nb * 4);
    int*    bpre   = (int*)alloc((size_t)nb * 4);
    float*  gcnt   = (float*)alloc(64 * 4);
    ushort* wfrag1 = (ushort*)alloc((size_t)64 * 64 * 16 * 2 * 2);   // K=64 hi+lo
    ushort* wfrag2 = (ushort*)alloc((size_t)256 * 64 * 16 * 2 * 2);  // K=256 hi+lo

    const int nzero = (int)(((char*)zend - (char*)cnt) / 4);

    // ---- merged zero pass + merged weight prep ----
    zero_int<<<(nzero + 255) / 256, 256, 0, stream>>>(cnt, nzero);
    prep_w_all<<<(64 * 64 + 256 * 64 + 255) / 256, 256, 0, stream>>>(
        g1_Wl, g1_Wr, wfrag1, g2_Wl, g2_Wr, wfrag2);

    // ---- CSR by dst ----
    deg_kernel<<<(E + 255) / 256, 256, 0, stream>>>(dst, cnt, E);
    scan_block<<<nb, 256, 0, stream>>>(cnt, off, bsum, N);
    scan_bsum<<<1, 512, 0, stream>>>(bsum, bpre, nb);
    scan_add<<<nb, 256, 0, stream>>>(off, bpre, N);
    scatter_kernel<<<(E + 255) / 256, 256, 0, stream>>>(dst, src, eattr, off, curp,
                                                        srcg, eag, E);

    // ---- encoder ----
    encoder_kernel<<<(N * 64 + 255) / 256, 256, 0, stream>>>(x, W_enc, b_enc, bufH0, N);

    const int gblocks = (N + 63) / 64;

    // ---- GAT layer 1: h0 -> XL(bufXL), XR(bufA); aggregate -> h1 in-place(bufA)
    gemm_mfma<64><<<gblocks, 512, 0, stream>>>(
        bufH0, wfrag1, g1_bl, g1_br, bufXL, bufA, N);
    gat_aggregate<<<(N + 3) / 4, 256, 0, stream>>>(
        bufXL, bufA, off, srcg, eag, g1_We, g1_att, g1_bias, bufA, N);

    // ---- GAT layer 2: h1(bufA) -> XL(bufXL), XR in-place(bufA); aggregate -> h2(bufA)
    gemm_mfma<256><<<gblocks, 512, 0, stream>>>(
        bufA, wfrag2, g2_bl, g2_br, bufXL, bufA, N);
    gat_aggregate<<<(N + 3) / 4, 256, 0, stream>>>(
        bufXL, bufA, off, srcg, eag, g2_We, g2_att, g2_bias, bufA, N);

    // ---- pool + MLP head ----
    pool_kernel<<<64 * 8, 256, 0, stream>>>(bufA, batch, pooled, gcnt, N);
    mlp_kernel<<<64, 128, 0, stream>>>(pooled, gcnt, W_p1, b_p1, ln_g, ln_b,
                                       W_p2, b_p2, W_head, b_head, (float*)d_out);
}